// Round 1
// baseline (509.249 us; speedup 1.0000x reference)
//
#include <hip/hip_runtime.h>
#include <hip/hip_bf16.h>
#include <stdint.h>

// Problem constants
constexpr int B_ = 8, N_ = 1024, DIM_ = 512, H_ = 8, D_ = 64;
constexpr int BH_ = B_ * H_;   // 64
constexpr int M_  = B_ * N_;   // 8192 rows
constexpr float SCALE_ = 0.04419417382415922f;  // 512^-0.5  (DIM, not D!)

typedef __bf16 bf16x8 __attribute__((ext_vector_type(8)));
typedef float  f32x4  __attribute__((ext_vector_type(4)));
typedef unsigned short u16;
typedef u16 u16x8 __attribute__((ext_vector_type(8)));
typedef u16 u16x4 __attribute__((ext_vector_type(4)));

static __device__ __forceinline__ u16 f2bf(float f) {
  uint32_t u = __builtin_bit_cast(uint32_t, f);
  u += 0x7FFFu + ((u >> 16) & 1u);           // RNE
  return (u16)(u >> 16);
}
static __device__ __forceinline__ bf16x8 ld8(const u16* p) {
  return __builtin_bit_cast(bf16x8, *reinterpret_cast<const u16x8*>(p));
}
static __device__ __forceinline__ f32x4 mfma16(bf16x8 a, bf16x8 b, f32x4 c) {
  return __builtin_amdgcn_mfma_f32_16x16x32_bf16(a, b, c, 0, 0, 0);
}

// ---------- pre-pass: f32 -> bf16 cast (vectorized x4) ----------
__global__ void k_cvt(const float* __restrict__ in, u16* __restrict__ out, int n4) {
  int i = blockIdx.x * blockDim.x + threadIdx.x;
  int stride = gridDim.x * blockDim.x;
  for (int idx = i; idx < n4; idx += stride) {
    float4 v = reinterpret_cast<const float4*>(in)[idx];
    u16x4 o;
    o[0] = f2bf(v.x); o[1] = f2bf(v.y); o[2] = f2bf(v.z); o[3] = f2bf(v.w);
    reinterpret_cast<u16x4*>(out)[idx] = o;
  }
}

// ---------- pre-pass: W[512][nc] f32 -> Wt[nc][512] bf16 ----------
__global__ void k_wt(const float* __restrict__ W, u16* __restrict__ Wt, int ncols) {
  int idx = blockIdx.x * 256 + threadIdx.x;
  if (idx >= ncols * 512) return;
  int c = idx >> 9, k = idx & 511;
  Wt[idx] = f2bf(W[k * ncols + c]);
}

// ---------- GEMM: A[M][512]bf16 @ Wt[NC][512]bf16^T + bias ----------
// MODE 0: scatter epilogue -> q,k [BH][N][D] bf16, v -> vt [BH][D][N] bf16
// MODE 1: plain f32 out [M][NC]
template<int NC, int MODE>
__global__ __launch_bounds__(256, 2) void k_gemm(
    const u16* __restrict__ A, const u16* __restrict__ Wt, const float* __restrict__ bias,
    u16* __restrict__ qo, u16* __restrict__ ko, u16* __restrict__ vto, float* __restrict__ fo)
{
  const int wv = threadIdx.x >> 6, ln = threadIdx.x & 63;
  const int lr = ln & 15, lg = ln >> 4;
  const int r0 = blockIdx.x * 128 + wv * 32;
  const int c0 = blockIdx.y * 64;
  const u16* Ap = A  + (size_t)(r0 + lr) * 512 + lg * 8;
  const u16* Bp = Wt + (size_t)(c0 + lr) * 512 + lg * 8;
  f32x4 acc[2][4] = {};
#pragma unroll 4
  for (int kk = 0; kk < 512; kk += 32) {
    bf16x8 a0 = ld8(Ap + kk);
    bf16x8 a1 = ld8(Ap + 16 * 512 + kk);
    bf16x8 b0 = ld8(Bp + kk);
    bf16x8 b1 = ld8(Bp + 16 * 512 + kk);
    bf16x8 b2 = ld8(Bp + 32 * 512 + kk);
    bf16x8 b3 = ld8(Bp + 48 * 512 + kk);
    acc[0][0] = mfma16(a0, b0, acc[0][0]);
    acc[0][1] = mfma16(a0, b1, acc[0][1]);
    acc[0][2] = mfma16(a0, b2, acc[0][2]);
    acc[0][3] = mfma16(a0, b3, acc[0][3]);
    acc[1][0] = mfma16(a1, b0, acc[1][0]);
    acc[1][1] = mfma16(a1, b1, acc[1][1]);
    acc[1][2] = mfma16(a1, b2, acc[1][2]);
    acc[1][3] = mfma16(a1, b3, acc[1][3]);
  }
#pragma unroll
  for (int am = 0; am < 2; ++am)
#pragma unroll
    for (int nb = 0; nb < 4; ++nb)
#pragma unroll
      for (int r = 0; r < 4; ++r) {
        int gr = r0 + am * 16 + lg * 4 + r;
        int gc = c0 + nb * 16 + lr;
        float v = acc[am][nb][r] + bias[gc];
        if (MODE == 0) {
          int part = gc >> 9, cc = gc & 511;
          int hh = cc >> 6, dd = cc & 63;
          int bb = gr >> 10, nn = gr & 1023;
          int bh = bb * H_ + hh;
          u16 bv = f2bf(v);
          if (part == 0)      qo[((size_t)(bh * N_ + nn)) * D_ + dd] = bv;
          else if (part == 1) ko[((size_t)(bh * N_ + nn)) * D_ + dd] = bv;
          else                vto[((size_t)(bh * D_ + dd)) * N_ + nn] = bv;
        } else {
          fo[(size_t)gr * NC + gc] = v;
        }
      }
}

// ---------- attention ----------
// STAGE 1: out1 = sigmoid(QK^T * mask) @ V        (no normalization)
// STAGE 2: out2 = softmax(QK^T * SCALE) @ V       (flash-style)
// Per wave: 16 query rows, full D=64 output. j-loop step 32.
template<int STAGE>
__global__ __launch_bounds__(256, 2) void k_attn(
    const u16* __restrict__ Q, const u16* __restrict__ K, const u16* __restrict__ Vt,
    const float* __restrict__ mask, u16* __restrict__ O)
{
  __shared__ u16 pbuf[4][16][40];   // per-wave P tile, rows padded to 40 (80B, 16B-aligned)
  const int wv = threadIdx.x >> 6, ln = threadIdx.x & 63;
  const int lr = ln & 15, lg = ln >> 4;
  const int bh = blockIdx.y;
  const int i0 = blockIdx.x * 64 + wv * 16;
  const size_t base = (size_t)bh * N_ * D_;   // same product for Vt ([D][N])

  bf16x8 aq0 = ld8(Q + base + (size_t)(i0 + lr) * D_ + lg * 8);
  bf16x8 aq1 = ld8(Q + base + (size_t)(i0 + lr) * D_ + 32 + lg * 8);

  f32x4 acco[4] = {};
  float mreg[4], ssum[4];
#pragma unroll
  for (int r = 0; r < 4; ++r) { mreg[r] = -3e30f; ssum[r] = 0.f; }

  for (int jt = 0; jt < N_; jt += 32) {
    f32x4 s[2];
#pragma unroll
    for (int js = 0; js < 2; ++js) {
      const u16* kp = K + base + (size_t)(jt + js * 16 + lr) * D_ + lg * 8;
      bf16x8 bk0 = ld8(kp);
      bf16x8 bk1 = ld8(kp + 32);
      f32x4 z = {};
      z = mfma16(aq0, bk0, z);
      z = mfma16(aq1, bk1, z);
      s[js] = z;
    }
    if (STAGE == 1) {
#pragma unroll
      for (int js = 0; js < 2; ++js)
#pragma unroll
        for (int r = 0; r < 4; ++r) {
          int gi = i0 + lg * 4 + r;
          int gj = jt + js * 16 + lr;
          float x = s[js][r] * mask[(size_t)gi * N_ + gj];
          float p = 1.f / (1.f + __expf(-x));
          pbuf[wv][lg * 4 + r][js * 16 + lr] = f2bf(p);
        }
    } else {
      float fac[4];
#pragma unroll
      for (int r = 0; r < 4; ++r) {
        float lg0 = s[0][r] * SCALE_;
        float lg1 = s[1][r] * SCALE_;
        float tm = fmaxf(lg0, lg1);
        tm = fmaxf(tm, __shfl_xor(tm, 1));
        tm = fmaxf(tm, __shfl_xor(tm, 2));
        tm = fmaxf(tm, __shfl_xor(tm, 4));
        tm = fmaxf(tm, __shfl_xor(tm, 8));
        float mnew = fmaxf(mreg[r], tm);
        float fc = __expf(mreg[r] - mnew);
        float p0 = __expf(lg0 - mnew);
        float p1 = __expf(lg1 - mnew);
        float rs = p0 + p1;
        rs += __shfl_xor(rs, 1);
        rs += __shfl_xor(rs, 2);
        rs += __shfl_xor(rs, 4);
        rs += __shfl_xor(rs, 8);
        ssum[r] = ssum[r] * fc + rs;
        mreg[r] = mnew;
        fac[r] = fc;
        pbuf[wv][lg * 4 + r][lr]      = f2bf(p0);
        pbuf[wv][lg * 4 + r][16 + lr] = f2bf(p1);
      }
#pragma unroll
      for (int db = 0; db < 4; ++db)
#pragma unroll
        for (int r = 0; r < 4; ++r) acco[db][r] *= fac[r];
    }
    // P A-fragment from LDS (row lr, cols lg*8..lg*8+7 of the 16x32 tile)
    bf16x8 ap = ld8(&pbuf[wv][lr][lg * 8]);
#pragma unroll
    for (int db = 0; db < 4; ++db) {
      bf16x8 bv = ld8(Vt + base + (size_t)(db * 16 + lr) * N_ + jt + lg * 8);
      acco[db] = mfma16(ap, bv, acco[db]);
    }
  }

  const int bb = bh >> 3, hh = bh & 7;
#pragma unroll
  for (int db = 0; db < 4; ++db)
#pragma unroll
    for (int r = 0; r < 4; ++r) {
      float v = acco[db][r];
      if (STAGE == 2) v /= ssum[r];
      int gi = i0 + lg * 4 + r;
      O[(size_t)(bb * N_ + gi) * DIM_ + hh * D_ + db * 16 + lr] = f2bf(v);
    }
}

extern "C" void kernel_launch(void* const* d_in, const int* in_sizes, int n_in,
                              void* d_out, int out_size, void* d_ws, size_t ws_size,
                              hipStream_t stream)
{
  const float* x    = (const float*)d_in[0];
  const float* mask = (const float*)d_in[1];
  const float* W1   = (const float*)d_in[2];
  const float* b1   = (const float*)d_in[3];
  const float* W2   = (const float*)d_in[4];
  const float* b2   = (const float*)d_in[5];
  const float* W3   = (const float*)d_in[6];
  const float* b3   = (const float*)d_in[7];
  float* out = (float*)d_out;

  // workspace carve-up (~44 MB total)
  char* ws = (char*)d_ws;
  size_t off = 0;
  auto alloc = [&](size_t bytes) { char* p = ws + off; off += (bytes + 255) & ~255ULL; return p; };
  u16* W1t = (u16*)alloc((size_t)1536 * 512 * 2);
  u16* W2t = (u16*)alloc((size_t)1536 * 512 * 2);
  u16* W3t = (u16*)alloc((size_t)512 * 512 * 2);
  u16* xb  = (u16*)alloc((size_t)M_ * DIM_ * 2);      // x bf16; reused as out2
  u16* q   = (u16*)alloc((size_t)BH_ * N_ * D_ * 2);
  u16* k   = (u16*)alloc((size_t)BH_ * N_ * D_ * 2);
  u16* vt  = (u16*)alloc((size_t)BH_ * N_ * D_ * 2);
  u16* o1  = (u16*)alloc((size_t)M_ * DIM_ * 2);
  u16* o2  = xb;

  k_cvt<<<4096, 256, 0, stream>>>(x, xb, M_ * DIM_ / 4);
  k_wt<<<(1536 * 512 + 255) / 256, 256, 0, stream>>>(W1, W1t, 1536);
  k_wt<<<(1536 * 512 + 255) / 256, 256, 0, stream>>>(W2, W2t, 1536);
  k_wt<<<(512 * 512 + 255) / 256, 256, 0, stream>>>(W3, W3t, 512);

  dim3 g1(M_ / 128, 1536 / 64);
  k_gemm<1536, 0><<<g1, 256, 0, stream>>>(xb, W1t, b1, q, k, vt, nullptr);

  dim3 ga(N_ / 64, BH_);
  k_attn<1><<<ga, 256, 0, stream>>>(q, k, vt, mask, o1);

  k_gemm<1536, 0><<<g1, 256, 0, stream>>>(o1, W2t, b2, q, k, vt, nullptr);

  k_attn<2><<<ga, 256, 0, stream>>>(q, k, vt, mask, o2);

  dim3 g3(M_ / 128, 512 / 64);
  k_gemm<512, 1><<<g3, 256, 0, stream>>>(o2, W3t, b3, nullptr, nullptr, nullptr, out);
}

// Round 2
// 269.962 us; speedup vs baseline: 1.8864x; 1.8864x over previous
//
#include <hip/hip_runtime.h>
#include <hip/hip_bf16.h>
#include <stdint.h>

// Problem constants
constexpr int B_ = 8, N_ = 1024, DIM_ = 512, H_ = 8, D_ = 64;
constexpr int BH_ = B_ * H_;   // 64
constexpr int M_  = B_ * N_;   // 8192 rows
constexpr float SCALE_ = 0.04419417382415922f;  // 512^-0.5  (DIM, not D!)

typedef __bf16 bf16x8 __attribute__((ext_vector_type(8)));
typedef float  f32x4  __attribute__((ext_vector_type(4)));
typedef unsigned short u16;
typedef u16 u16x8 __attribute__((ext_vector_type(8)));
typedef u16 u16x4 __attribute__((ext_vector_type(4)));

static __device__ __forceinline__ u16 f2bf(float f) {
  uint32_t u = __builtin_bit_cast(uint32_t, f);
  u += 0x7FFFu + ((u >> 16) & 1u);           // RNE
  return (u16)(u >> 16);
}
static __device__ __forceinline__ bf16x8 ld8(const u16* p) {
  return __builtin_bit_cast(bf16x8, *reinterpret_cast<const u16x8*>(p));
}
static __device__ __forceinline__ f32x4 mfma16(bf16x8 a, bf16x8 b, f32x4 c) {
  return __builtin_amdgcn_mfma_f32_16x16x32_bf16(a, b, c, 0, 0, 0);
}
// async global->LDS, 16B per lane; lds dest = wave-uniform base + lane*16 (HW adds lane offset)
static __device__ __forceinline__ void gload_lds16(const u16* g, void* l) {
  __builtin_amdgcn_global_load_lds(
      (const __attribute__((address_space(1))) void*)g,
      (__attribute__((address_space(3))) void*)l, 16, 0, 0);
}

// ---------- pre-pass: f32 -> bf16 cast (vectorized x4) ----------
__global__ void k_cvt(const float* __restrict__ in, u16* __restrict__ out, int n4) {
  int i = blockIdx.x * blockDim.x + threadIdx.x;
  int stride = gridDim.x * blockDim.x;
  for (int idx = i; idx < n4; idx += stride) {
    float4 v = reinterpret_cast<const float4*>(in)[idx];
    u16x4 o;
    o[0] = f2bf(v.x); o[1] = f2bf(v.y); o[2] = f2bf(v.z); o[3] = f2bf(v.w);
    reinterpret_cast<u16x4*>(out)[idx] = o;
  }
}

// ---------- pre-pass: W[512][nc] f32 -> Wt[nc][512] bf16 ----------
__global__ void k_wt(const float* __restrict__ W, u16* __restrict__ Wt, int ncols) {
  int idx = blockIdx.x * 256 + threadIdx.x;
  if (idx >= ncols * 512) return;
  int c = idx >> 9, k = idx & 511;
  Wt[idx] = f2bf(W[k * ncols + c]);
}

// ---------- GEMM (m97 structure): 128x128 tile, BK=32, LDS double-buffered ----------
// A[M][512] bf16, Wt[NC][512] bf16 (B^T). MODE 0: scatter q/k/vt epilogue; MODE 1: f32 out.
// LDS tiles [128][32] bf16 (64B rows), XOR swizzle: byte ^= ((row>>1)&3)<<4 so
// ds_read_b128 column-slices spread across all 8 bank-quads (2-way = free).
template<int NC, int MODE>
__global__ __launch_bounds__(256) void k_gemm(
    const u16* __restrict__ A, const u16* __restrict__ Wt, const float* __restrict__ bias,
    u16* __restrict__ qo, u16* __restrict__ ko, u16* __restrict__ vto, float* __restrict__ fo)
{
  __shared__ __attribute__((aligned(16))) u16 As[2][128 * 32];
  __shared__ __attribute__((aligned(16))) u16 Bs[2][128 * 32];
  const int wv = threadIdx.x >> 6, ln = threadIdx.x & 63;
  const int lr = ln & 15, lg = ln >> 4;
  const int wr = wv >> 1, wc = wv & 1;
  const int r0 = blockIdx.x * 128;
  const int c0 = blockIdx.y * 128;

  // staging: per tile 8KB = 8 issues of 1KB; wave wv does issues {2wv, 2wv+1}
  auto stage = [&](int bufi, int kk) {
#pragma unroll
    for (int q = 0; q < 2; ++q) {
      int L = (wv * 2 + q) * 1024 + ln * 16;   // linear swizzled LDS byte offset
      int row = L >> 6;
      int col = ((L & 63) ^ (((row >> 1) & 3) << 4)) >> 1;  // inverse-swizzled source col
      gload_lds16(A  + (size_t)(r0 + row) * 512 + kk + col, (char*)As[bufi] + (wv * 2 + q) * 1024);
      gload_lds16(Wt + (size_t)(c0 + row) * 512 + kk + col, (char*)Bs[bufi] + (wv * 2 + q) * 1024);
    }
  };
  auto swzld = [&](const u16* tile, int row, int colb) -> bf16x8 {
    int byte = (row << 6) + (colb ^ (((row >> 1) & 3) << 4));
    return __builtin_bit_cast(bf16x8, *reinterpret_cast<const u16x8*>((const char*)tile + byte));
  };

  f32x4 acc[4][4] = {};
  stage(0, 0);
  int buf = 0;
  for (int kk = 0; kk < 512; kk += 32) {
    __syncthreads();                       // drains vmcnt: buf's tiles ready, prev reads done
    if (kk + 32 < 512) stage(buf ^ 1, kk + 32);  // async prefetch, in flight during compute
    bf16x8 af[4], bfb[4];
#pragma unroll
    for (int m = 0; m < 4; ++m) af[m]  = swzld(As[buf], wr * 64 + m * 16 + lr, lg * 16);
#pragma unroll
    for (int n = 0; n < 4; ++n) bfb[n] = swzld(Bs[buf], wc * 64 + n * 16 + lr, lg * 16);
#pragma unroll
    for (int m = 0; m < 4; ++m)
#pragma unroll
      for (int n = 0; n < 4; ++n)
        acc[m][n] = mfma16(af[m], bfb[n], acc[m][n]);
    buf ^= 1;
  }

#pragma unroll
  for (int m = 0; m < 4; ++m)
#pragma unroll
    for (int n = 0; n < 4; ++n)
#pragma unroll
      for (int r = 0; r < 4; ++r) {
        int gr = r0 + wr * 64 + m * 16 + lg * 4 + r;
        int gc = c0 + wc * 64 + n * 16 + lr;
        float v = acc[m][n][r] + bias[gc];
        if (MODE == 0) {
          int part = gc >> 9, cc = gc & 511;
          int hh = cc >> 6, dd = cc & 63;
          int bb = gr >> 10, nn = gr & 1023;
          int bh = bb * H_ + hh;
          u16 bv = f2bf(v);
          if (part == 0)      qo[((size_t)(bh * N_ + nn)) * D_ + dd] = bv;
          else if (part == 1) ko[((size_t)(bh * N_ + nn)) * D_ + dd] = bv;
          else                vto[((size_t)(bh * D_ + dd)) * N_ + nn] = bv;
        } else {
          fo[(size_t)gr * NC + gc] = v;
        }
      }
}

// ---------- attention ----------
// STAGE 1: out1 = sigmoid(QK^T * mask) @ V        (no normalization)
// STAGE 2: out2 = softmax(QK^T * SCALE) @ V       (flash-style online)
// 512 threads = 8 waves, each wave 16 query rows; j-step 64.
// K tile [64 j][64 d] and Vt tile [64 d][64 j] bf16 in LDS (128B rows),
// double-buffered, XOR swizzle byte ^= ((row&7)<<4) (G4 fix for 128B-stride reads).
template<int STAGE>
__global__ __launch_bounds__(512, 4) void k_attn(
    const u16* __restrict__ Q, const u16* __restrict__ K, const u16* __restrict__ Vt,
    const float* __restrict__ mask, u16* __restrict__ O)
{
  __shared__ __attribute__((aligned(16))) u16 Kb[2][64 * 64];
  __shared__ __attribute__((aligned(16))) u16 Vb[2][64 * 64];
  __shared__ __attribute__((aligned(16))) u16 pbuf[8][16][72];  // rows padded to 144B
  const int wv = threadIdx.x >> 6, ln = threadIdx.x & 63;
  const int lr = ln & 15, lg = ln >> 4;
  const int bh = blockIdx.y;
  const int i0 = blockIdx.x * 128 + wv * 16;
  const size_t base = (size_t)bh * N_ * D_;   // same product for Vt ([D][N])

  // stage K/V tiles for window jt2: 8 waves x 1KB each per tile
  auto stageKV = [&](int bufi, int jt2) {
    int L = wv * 1024 + ln * 16;
    int row = L >> 7;
    int col = ((L & 127) ^ ((row & 7) << 4)) >> 1;   // inverse-swizzled source col
    gload_lds16(K  + base + (size_t)(jt2 + row) * 64 + col,  (char*)Kb[bufi] + wv * 1024);
    gload_lds16(Vt + base + (size_t)row * 1024 + jt2 + col,  (char*)Vb[bufi] + wv * 1024);
  };
  auto swzld = [&](const u16* tile, int row, int colb) -> bf16x8 {
    int byte = (row << 7) + (colb ^ ((row & 7) << 4));
    return __builtin_bit_cast(bf16x8, *reinterpret_cast<const u16x8*>((const char*)tile + byte));
  };

  bf16x8 aq0 = ld8(Q + base + (size_t)(i0 + lr) * D_ + lg * 8);
  bf16x8 aq1 = ld8(Q + base + (size_t)(i0 + lr) * D_ + 32 + lg * 8);

  f32x4 acco[4] = {};
  float mreg[4], ssum[4];
#pragma unroll
  for (int r = 0; r < 4; ++r) { mreg[r] = -3e30f; ssum[r] = 0.f; }

  stageKV(0, 0);
  int buf = 0;
  for (int jt = 0; jt < N_; jt += 64) {
    __syncthreads();                       // buf's K/V ready; prev iter's reads done
    if (jt + 64 < N_) stageKV(buf ^ 1, jt + 64);

    // QK^T: 16 rows x 64 cols per wave
    f32x4 s[4];
#pragma unroll
    for (int js = 0; js < 4; ++js) {
      int krow = js * 16 + lr;
      bf16x8 bk0 = swzld(Kb[buf], krow, lg * 16);
      bf16x8 bk1 = swzld(Kb[buf], krow, 64 + lg * 16);
      f32x4 z = {};
      z = mfma16(aq0, bk0, z);
      z = mfma16(aq1, bk1, z);
      s[js] = z;
    }

    if (STAGE == 1) {
#pragma unroll
      for (int js = 0; js < 4; ++js)
#pragma unroll
        for (int r = 0; r < 4; ++r) {
          int gi = i0 + lg * 4 + r;
          int gj = jt + js * 16 + lr;
          float x = s[js][r] * mask[(size_t)gi * N_ + gj];
          float p = 1.f / (1.f + __expf(-x));
          pbuf[wv][lg * 4 + r][js * 16 + lr] = f2bf(p);
        }
    } else {
      float fac[4];
#pragma unroll
      for (int r = 0; r < 4; ++r) {
        float l0 = s[0][r] * SCALE_;
        float l1 = s[1][r] * SCALE_;
        float l2 = s[2][r] * SCALE_;
        float l3 = s[3][r] * SCALE_;
        float tm = fmaxf(fmaxf(l0, l1), fmaxf(l2, l3));
        tm = fmaxf(tm, __shfl_xor(tm, 1));
        tm = fmaxf(tm, __shfl_xor(tm, 2));
        tm = fmaxf(tm, __shfl_xor(tm, 4));
        tm = fmaxf(tm, __shfl_xor(tm, 8));
        float mnew = fmaxf(mreg[r], tm);
        float fc = __expf(mreg[r] - mnew);
        float p0 = __expf(l0 - mnew);
        float p1 = __expf(l1 - mnew);
        float p2 = __expf(l2 - mnew);
        float p3 = __expf(l3 - mnew);
        float rs = (p0 + p1) + (p2 + p3);
        rs += __shfl_xor(rs, 1);
        rs += __shfl_xor(rs, 2);
        rs += __shfl_xor(rs, 4);
        rs += __shfl_xor(rs, 8);
        ssum[r] = ssum[r] * fc + rs;
        mreg[r] = mnew;
        fac[r] = fc;
        int prow = lg * 4 + r;
        pbuf[wv][prow][lr]      = f2bf(p0);
        pbuf[wv][prow][16 + lr] = f2bf(p1);
        pbuf[wv][prow][32 + lr] = f2bf(p2);
        pbuf[wv][prow][48 + lr] = f2bf(p3);
      }
#pragma unroll
      for (int db = 0; db < 4; ++db)
#pragma unroll
        for (int r = 0; r < 4; ++r) acco[db][r] *= fac[r];
    }

    // PV: P[16x64] @ V[64x64]
    bf16x8 ap0 = ld8(&pbuf[wv][lr][lg * 8]);
    bf16x8 ap1 = ld8(&pbuf[wv][lr][32 + lg * 8]);
#pragma unroll
    for (int db = 0; db < 4; ++db) {
      bf16x8 bv0 = swzld(Vb[buf], db * 16 + lr, lg * 16);
      bf16x8 bv1 = swzld(Vb[buf], db * 16 + lr, 64 + lg * 16);
      acco[db] = mfma16(ap1, bv1, mfma16(ap0, bv0, acco[db]));
    }
    buf ^= 1;
  }

  const int bb = bh >> 3, hh = bh & 7;
#pragma unroll
  for (int db = 0; db < 4; ++db)
#pragma unroll
    for (int r = 0; r < 4; ++r) {
      float v = acco[db][r];
      if (STAGE == 2) v /= ssum[r];
      int gi = i0 + lg * 4 + r;
      O[(size_t)(bb * N_ + gi) * DIM_ + hh * D_ + db * 16 + lr] = f2bf(v);
    }
}

extern "C" void kernel_launch(void* const* d_in, const int* in_sizes, int n_in,
                              void* d_out, int out_size, void* d_ws, size_t ws_size,
                              hipStream_t stream)
{
  const float* x    = (const float*)d_in[0];
  const float* mask = (const float*)d_in[1];
  const float* W1   = (const float*)d_in[2];
  const float* b1   = (const float*)d_in[3];
  const float* W2   = (const float*)d_in[4];
  const float* b2   = (const float*)d_in[5];
  const float* W3   = (const float*)d_in[6];
  const float* b3   = (const float*)d_in[7];
  float* out = (float*)d_out;

  // workspace carve-up (~44 MB total)
  char* ws = (char*)d_ws;
  size_t off = 0;
  auto alloc = [&](size_t bytes) { char* p = ws + off; off += (bytes + 255) & ~255ULL; return p; };
  u16* W1t = (u16*)alloc((size_t)1536 * 512 * 2);
  u16* W2t = (u16*)alloc((size_t)1536 * 512 * 2);
  u16* W3t = (u16*)alloc((size_t)512 * 512 * 2);
  u16* xb  = (u16*)alloc((size_t)M_ * DIM_ * 2);      // x bf16; reused as out2
  u16* q   = (u16*)alloc((size_t)BH_ * N_ * D_ * 2);
  u16* k   = (u16*)alloc((size_t)BH_ * N_ * D_ * 2);
  u16* vt  = (u16*)alloc((size_t)BH_ * N_ * D_ * 2);
  u16* o1  = (u16*)alloc((size_t)M_ * DIM_ * 2);
  u16* o2  = xb;

  k_cvt<<<4096, 256, 0, stream>>>(x, xb, M_ * DIM_ / 4);
  k_wt<<<(1536 * 512 + 255) / 256, 256, 0, stream>>>(W1, W1t, 1536);
  k_wt<<<(1536 * 512 + 255) / 256, 256, 0, stream>>>(W2, W2t, 1536);
  k_wt<<<(512 * 512 + 255) / 256, 256, 0, stream>>>(W3, W3t, 512);

  dim3 g1(M_ / 128, 1536 / 128);
  k_gemm<1536, 0><<<g1, 256, 0, stream>>>(xb, W1t, b1, q, k, vt, nullptr);

  dim3 ga(N_ / 128, BH_);
  k_attn<1><<<ga, 512, 0, stream>>>(q, k, vt, mask, o1);

  k_gemm<1536, 0><<<g1, 256, 0, stream>>>(o1, W2t, b2, q, k, vt, nullptr);

  k_attn<2><<<ga, 512, 0, stream>>>(q, k, vt, mask, o2);

  dim3 g3(M_ / 128, 512 / 128);
  k_gemm<512, 1><<<g3, 256, 0, stream>>>(o2, W3t, b3, nullptr, nullptr, nullptr, out);
}

// Round 3
// 252.511 us; speedup vs baseline: 2.0167x; 1.0691x over previous
//
#include <hip/hip_runtime.h>
#include <hip/hip_bf16.h>
#include <stdint.h>

// Problem constants
constexpr int B_ = 8, N_ = 1024, DIM_ = 512, H_ = 8, D_ = 64;
constexpr int BH_ = B_ * H_;   // 64
constexpr int M_  = B_ * N_;   // 8192 rows
constexpr float SCALE_ = 0.04419417382415922f;    // 512^-0.5  (DIM, not D!)
constexpr float LOG2E_ = 1.44269504088896f;
constexpr float QSL2E_ = SCALE_ * LOG2E_;         // folded into W2 q-columns

typedef __bf16 bf16x8 __attribute__((ext_vector_type(8)));
typedef float  f32x4  __attribute__((ext_vector_type(4)));
typedef unsigned short u16;
typedef u16 u16x8 __attribute__((ext_vector_type(8)));
typedef u16 u16x4 __attribute__((ext_vector_type(4)));

static __device__ __forceinline__ u16 f2bf(float f) {
  uint32_t u = __builtin_bit_cast(uint32_t, f);
  u += 0x7FFFu + ((u >> 16) & 1u);           // RNE
  return (u16)(u >> 16);
}
static __device__ __forceinline__ bf16x8 ld8(const u16* p) {
  return __builtin_bit_cast(bf16x8, *reinterpret_cast<const u16x8*>(p));
}
static __device__ __forceinline__ f32x4 mfma16(bf16x8 a, bf16x8 b, f32x4 c) {
  return __builtin_amdgcn_mfma_f32_16x16x32_bf16(a, b, c, 0, 0, 0);
}
// async global->LDS, 16B per lane; lds dest = wave-uniform base + lane*16
static __device__ __forceinline__ void gload_lds16(const u16* g, void* l) {
  __builtin_amdgcn_global_load_lds(
      (const __attribute__((address_space(1))) void*)g,
      (__attribute__((address_space(3))) void*)l, 16, 0, 0);
}

// ---------- pre-pass: f32 -> bf16 cast (vectorized x4) ----------
__global__ void k_cvt(const float* __restrict__ in, u16* __restrict__ out, int n4) {
  int i = blockIdx.x * blockDim.x + threadIdx.x;
  int stride = gridDim.x * blockDim.x;
  for (int idx = i; idx < n4; idx += stride) {
    float4 v = reinterpret_cast<const float4*>(in)[idx];
    u16x4 o;
    o[0] = f2bf(v.x); o[1] = f2bf(v.y); o[2] = f2bf(v.z); o[3] = f2bf(v.w);
    reinterpret_cast<u16x4*>(out)[idx] = o;
  }
}

// ---------- pre-pass: mask * (-log2e)  (for stage-1 sigmoid via exp2) ----------
__global__ void k_mask(const float* __restrict__ in, float* __restrict__ out, int n4) {
  int i = blockIdx.x * blockDim.x + threadIdx.x;
  int stride = gridDim.x * blockDim.x;
  for (int idx = i; idx < n4; idx += stride) {
    float4 v = reinterpret_cast<const float4*>(in)[idx];
    v.x *= -LOG2E_; v.y *= -LOG2E_; v.z *= -LOG2E_; v.w *= -LOG2E_;
    reinterpret_cast<float4*>(out)[idx] = v;
  }
}

// ---------- pre-pass: W[512][nc] f32 -> Wt[nc][512] bf16, cols<512 scaled by qs ----------
__global__ void k_wt(const float* __restrict__ W, u16* __restrict__ Wt, int ncols, float qs) {
  int idx = blockIdx.x * 256 + threadIdx.x;
  if (idx >= ncols * 512) return;
  int c = idx >> 9, k = idx & 511;
  float v = W[k * ncols + c];
  if (c < 512) v *= qs;
  Wt[idx] = f2bf(v);
}

// ---------- GEMM (m97 structure): 128x128 tile, BK=32, LDS double-buffered ----------
// MODE 0: scatter epilogue -> q,k [BH][N][D] bf16, v -> vt [BH][D][N] bf16. MODE 1: f32 out.
// SQ: scale bias of q-part (cols<512) by QSL2E_ to match the W-fold.
template<int NC, int MODE, bool SQ>
__global__ __launch_bounds__(256) void k_gemm(
    const u16* __restrict__ A, const u16* __restrict__ Wt, const float* __restrict__ bias,
    u16* __restrict__ qo, u16* __restrict__ ko, u16* __restrict__ vto, float* __restrict__ fo)
{
  __shared__ __attribute__((aligned(16))) u16 As[2][128 * 32];
  __shared__ __attribute__((aligned(16))) u16 Bs[2][128 * 32];
  const int wv = threadIdx.x >> 6, ln = threadIdx.x & 63;
  const int lr = ln & 15, lg = ln >> 4;
  const int wr = wv >> 1, wc = wv & 1;
  const int r0 = blockIdx.x * 128;
  const int c0 = blockIdx.y * 128;

  auto stage = [&](int bufi, int kk) {
#pragma unroll
    for (int q = 0; q < 2; ++q) {
      int L = (wv * 2 + q) * 1024 + ln * 16;   // linear swizzled LDS byte offset
      int row = L >> 6;
      int col = ((L & 63) ^ (((row >> 1) & 3) << 4)) >> 1;  // inverse-swizzled source col
      gload_lds16(A  + (size_t)(r0 + row) * 512 + kk + col, (char*)As[bufi] + (wv * 2 + q) * 1024);
      gload_lds16(Wt + (size_t)(c0 + row) * 512 + kk + col, (char*)Bs[bufi] + (wv * 2 + q) * 1024);
    }
  };
  auto swzld = [&](const u16* tile, int row, int colb) -> bf16x8 {
    int byte = (row << 6) + (colb ^ (((row >> 1) & 3) << 4));
    return __builtin_bit_cast(bf16x8, *reinterpret_cast<const u16x8*>((const char*)tile + byte));
  };

  f32x4 acc[4][4] = {};
  stage(0, 0);
  int buf = 0;
  for (int kk = 0; kk < 512; kk += 32) {
    __syncthreads();
    if (kk + 32 < 512) stage(buf ^ 1, kk + 32);
    bf16x8 af[4], bfb[4];
#pragma unroll
    for (int m = 0; m < 4; ++m) af[m]  = swzld(As[buf], wr * 64 + m * 16 + lr, lg * 16);
#pragma unroll
    for (int n = 0; n < 4; ++n) bfb[n] = swzld(Bs[buf], wc * 64 + n * 16 + lr, lg * 16);
#pragma unroll
    for (int m = 0; m < 4; ++m)
#pragma unroll
      for (int n = 0; n < 4; ++n)
        acc[m][n] = mfma16(af[m], bfb[n], acc[m][n]);
    buf ^= 1;
  }

#pragma unroll
  for (int m = 0; m < 4; ++m)
#pragma unroll
    for (int n = 0; n < 4; ++n)
#pragma unroll
      for (int r = 0; r < 4; ++r) {
        int gr = r0 + wr * 64 + m * 16 + lg * 4 + r;
        int gc = c0 + wc * 64 + n * 16 + lr;
        float bsc = (SQ && gc < 512) ? QSL2E_ : 1.f;
        float v = acc[m][n][r] + bias[gc] * bsc;
        if (MODE == 0) {
          int part = gc >> 9, cc = gc & 511;
          int hh = cc >> 6, dd = cc & 63;
          int bb = gr >> 10, nn = gr & 1023;
          int bh = bb * H_ + hh;
          u16 bv = f2bf(v);
          if (part == 0)      qo[((size_t)(bh * N_ + nn)) * D_ + dd] = bv;
          else if (part == 1) ko[((size_t)(bh * N_ + nn)) * D_ + dd] = bv;
          else                vto[((size_t)(bh * D_ + dd)) * N_ + nn] = bv;
        } else {
          fo[(size_t)gr * NC + gc] = v;
        }
      }
}

// ---------- attention (swapped-QK^T) ----------
// QK^T computed as mfma(K_frag, Q_frag) -> lane holds S^T[j][i]: i = lr (one query
// per lane), j = js*16 + lg*4 + r (16 keys per lane). Softmax/sigmoid row-work is
// lane-local; P stored to LDS row-major [i][j] with ds_write_b64; PV reads it back
// as a standard A-fragment (ds_read_b128).
// STAGE 1: P = sigmoid(S * mask)           mask pre-scaled by -log2e
// STAGE 2: P = exp2(S') unnormalized       SCALE*log2e folded into W2 q-cols; /sum at end
template<int STAGE>
__global__ __launch_bounds__(512, 4) void k_attn(
    const u16* __restrict__ Q, const u16* __restrict__ K, const u16* __restrict__ Vt,
    const float* __restrict__ mask, u16* __restrict__ O)
{
  __shared__ __attribute__((aligned(16))) u16 Kb[2][64 * 64];
  __shared__ __attribute__((aligned(16))) u16 Vb[2][64 * 64];
  __shared__ __attribute__((aligned(16))) u16 pbuf[8][16][72];
  const int wv = threadIdx.x >> 6, ln = threadIdx.x & 63;
  const int lr = ln & 15, lg = ln >> 4;
  const int bh = blockIdx.y;
  const int i0 = blockIdx.x * 128 + wv * 16;
  const size_t base = (size_t)bh * N_ * D_;

  auto stageKV = [&](int bufi, int jt2) {
    int L = wv * 1024 + ln * 16;
    int row = L >> 7;
    int col = ((L & 127) ^ ((row & 7) << 4)) >> 1;
    gload_lds16(K  + base + (size_t)(jt2 + row) * 64 + col,  (char*)Kb[bufi] + wv * 1024);
    gload_lds16(Vt + base + (size_t)row * 1024 + jt2 + col,  (char*)Vb[bufi] + wv * 1024);
  };
  auto swzld = [&](const u16* tile, int row, int colb) -> bf16x8 {
    int byte = (row << 7) + (colb ^ ((row & 7) << 4));
    return __builtin_bit_cast(bf16x8, *reinterpret_cast<const u16x8*>((const char*)tile + byte));
  };

  // Q as the B-operand: lane holds query row i=lr, k-elems d = lg*8..+7
  bf16x8 aq0 = ld8(Q + base + (size_t)(i0 + lr) * D_ + lg * 8);
  bf16x8 aq1 = ld8(Q + base + (size_t)(i0 + lr) * D_ + 32 + lg * 8);

  f32x4 acco[4] = {};
  float ssum_ln = 0.f;    // per-lane partial softmax denom (for query i=lr)

  stageKV(0, 0);
  int buf = 0;
  for (int jt = 0; jt < N_; jt += 64) {
    __syncthreads();
    if (jt + 64 < N_) stageKV(buf ^ 1, jt + 64);

    // S^T tiles: A = K rows j, B = Q rows i
    f32x4 s[4];
    __builtin_amdgcn_s_setprio(1);
#pragma unroll
    for (int js = 0; js < 4; ++js) {
      int krow = js * 16 + lr;
      bf16x8 bk0 = swzld(Kb[buf], krow, lg * 16);
      bf16x8 bk1 = swzld(Kb[buf], krow, 64 + lg * 16);
      f32x4 z = {};
      z = mfma16(bk0, aq0, z);
      z = mfma16(bk1, aq1, z);
      s[js] = z;
    }
    __builtin_amdgcn_s_setprio(0);

    if (STAGE == 1) {
#pragma unroll
      for (int js = 0; js < 4; ++js) {
        const float4 mk = *reinterpret_cast<const float4*>(
            &mask[(size_t)(i0 + lr) * N_ + jt + js * 16 + lg * 4]);
        u16x4 w;
#pragma unroll
        for (int r = 0; r < 4; ++r) {
          float mkr = (r == 0) ? mk.x : (r == 1) ? mk.y : (r == 2) ? mk.z : mk.w;
          float e = exp2f(s[js][r] * mkr);               // exp(-x*mask')
          float p = __builtin_amdgcn_rcpf(1.f + e);      // sigmoid
          w[r] = f2bf(p);
        }
        *reinterpret_cast<u16x4*>(&pbuf[wv][lr][js * 16 + lg * 4]) = w;
      }
    } else {
      float ps = 0.f;
#pragma unroll
      for (int js = 0; js < 4; ++js) {
        u16x4 w;
#pragma unroll
        for (int r = 0; r < 4; ++r) {
          float p = exp2f(s[js][r]);                     // unnormalized, logits bounded
          ps += p;
          w[r] = f2bf(p);
        }
        *reinterpret_cast<u16x4*>(&pbuf[wv][lr][js * 16 + lg * 4]) = w;
      }
      ssum_ln += ps;
    }

    // PV: P[16x64] @ V[64x64]
    bf16x8 ap0 = ld8(&pbuf[wv][lr][lg * 8]);
    bf16x8 ap1 = ld8(&pbuf[wv][lr][32 + lg * 8]);
    __builtin_amdgcn_s_setprio(1);
#pragma unroll
    for (int db = 0; db < 4; ++db) {
      bf16x8 bv0 = swzld(Vb[buf], db * 16 + lr, lg * 16);
      bf16x8 bv1 = swzld(Vb[buf], db * 16 + lr, 64 + lg * 16);
      acco[db] = mfma16(ap1, bv1, mfma16(ap0, bv0, acco[db]));
    }
    __builtin_amdgcn_s_setprio(0);
    buf ^= 1;
  }

  float inv[4];
  if (STAGE == 2) {
    float st = ssum_ln;
    st += __shfl_xor(st, 16);
    st += __shfl_xor(st, 32);    // now total denom for query i=lr (uniform over lg)
#pragma unroll
    for (int r = 0; r < 4; ++r)
      inv[r] = __builtin_amdgcn_rcpf(__shfl(st, lg * 4 + r));  // denom for output row
  }

  const int bb = bh >> 3, hh = bh & 7;
#pragma unroll
  for (int db = 0; db < 4; ++db)
#pragma unroll
    for (int r = 0; r < 4; ++r) {
      float v = acco[db][r];
      if (STAGE == 2) v *= inv[r];
      int gi = i0 + lg * 4 + r;
      O[(size_t)(bb * N_ + gi) * DIM_ + hh * D_ + db * 16 + lr] = f2bf(v);
    }
}

extern "C" void kernel_launch(void* const* d_in, const int* in_sizes, int n_in,
                              void* d_out, int out_size, void* d_ws, size_t ws_size,
                              hipStream_t stream)
{
  const float* x    = (const float*)d_in[0];
  const float* mask = (const float*)d_in[1];
  const float* W1   = (const float*)d_in[2];
  const float* b1   = (const float*)d_in[3];
  const float* W2   = (const float*)d_in[4];
  const float* b2   = (const float*)d_in[5];
  const float* W3   = (const float*)d_in[6];
  const float* b3   = (const float*)d_in[7];
  float* out = (float*)d_out;

  char* ws = (char*)d_ws;
  size_t off = 0;
  auto alloc = [&](size_t bytes) { char* p = ws + off; off += (bytes + 255) & ~255ULL; return p; };
  u16*   W1t = (u16*)alloc((size_t)1536 * 512 * 2);
  u16*   W2t = (u16*)alloc((size_t)1536 * 512 * 2);
  u16*   W3t = (u16*)alloc((size_t)512 * 512 * 2);
  u16*   xb  = (u16*)alloc((size_t)M_ * DIM_ * 2);      // x bf16; reused as out2
  u16*   q   = (u16*)alloc((size_t)BH_ * N_ * D_ * 2);
  u16*   k   = (u16*)alloc((size_t)BH_ * N_ * D_ * 2);
  u16*   vt  = (u16*)alloc((size_t)BH_ * N_ * D_ * 2);
  u16*   o1  = (u16*)alloc((size_t)M_ * DIM_ * 2);
  float* mk  = (float*)alloc((size_t)N_ * N_ * 4);      // mask * (-log2e)
  u16*   o2  = xb;

  k_cvt<<<2048, 256, 0, stream>>>(x, xb, M_ * DIM_ / 4);
  k_mask<<<1024, 256, 0, stream>>>(mask, mk, N_ * N_ / 4);
  k_wt<<<(1536 * 512 + 255) / 256, 256, 0, stream>>>(W1, W1t, 1536, 1.f);
  k_wt<<<(1536 * 512 + 255) / 256, 256, 0, stream>>>(W2, W2t, 1536, QSL2E_);
  k_wt<<<(512 * 512 + 255) / 256, 256, 0, stream>>>(W3, W3t, 512, 1.f);

  dim3 g1(M_ / 128, 1536 / 128);
  k_gemm<1536, 0, false><<<g1, 256, 0, stream>>>(xb, W1t, b1, q, k, vt, nullptr);

  dim3 ga(N_ / 128, BH_);
  k_attn<1><<<ga, 512, 0, stream>>>(q, k, vt, mk, o1);

  k_gemm<1536, 0, true><<<g1, 256, 0, stream>>>(o1, W2t, b2, q, k, vt, nullptr);

  k_attn<2><<<ga, 512, 0, stream>>>(q, k, vt, mk, o2);

  dim3 g3(M_ / 128, 512 / 128);
  k_gemm<512, 1, false><<<g3, 256, 0, stream>>>(o2, W3t, b3, nullptr, nullptr, nullptr, out);
}

// Round 4
// 228.468 us; speedup vs baseline: 2.2290x; 1.1052x over previous
//
#include <hip/hip_runtime.h>
#include <hip/hip_bf16.h>
#include <stdint.h>

// Problem constants
constexpr int B_ = 8, N_ = 1024, DIM_ = 512, H_ = 8, D_ = 64;
constexpr int BH_ = B_ * H_;   // 64
constexpr int M_  = B_ * N_;   // 8192 rows
constexpr float SCALE_ = 0.04419417382415922f;    // 512^-0.5  (DIM, not D!)
constexpr float LOG2E_ = 1.44269504088896f;
constexpr float QSL2E_ = SCALE_ * LOG2E_;         // folded into W2 q-columns

typedef __bf16 bf16x8 __attribute__((ext_vector_type(8)));
typedef float  f32x4  __attribute__((ext_vector_type(4)));
typedef unsigned short u16;
typedef u16 u16x8 __attribute__((ext_vector_type(8)));
typedef u16 u16x4 __attribute__((ext_vector_type(4)));

// native convert -> compiler emits v_cvt_pk_bf16_f32 for pairs (RNE)
static __device__ __forceinline__ u16 f2bf(float f) {
  return __builtin_bit_cast(u16, (__bf16)f);
}
static __device__ __forceinline__ bf16x8 ld8(const u16* p) {
  return __builtin_bit_cast(bf16x8, *reinterpret_cast<const u16x8*>(p));
}
static __device__ __forceinline__ f32x4 mfma16(bf16x8 a, bf16x8 b, f32x4 c) {
  return __builtin_amdgcn_mfma_f32_16x16x32_bf16(a, b, c, 0, 0, 0);
}
// async global->LDS, 16B per lane; lds dest = wave-uniform base + lane*16
static __device__ __forceinline__ void gload_lds16(const u16* g, void* l) {
  __builtin_amdgcn_global_load_lds(
      (const __attribute__((address_space(1))) void*)g,
      (__attribute__((address_space(3))) void*)l, 16, 0, 0);
}

// ---------- pre-pass: f32 -> bf16 cast (vectorized x4) ----------
__global__ void k_cvt(const float* __restrict__ in, u16* __restrict__ out, int n4) {
  int i = blockIdx.x * blockDim.x + threadIdx.x;
  int stride = gridDim.x * blockDim.x;
  for (int idx = i; idx < n4; idx += stride) {
    float4 v = reinterpret_cast<const float4*>(in)[idx];
    u16x4 o;
    o[0] = f2bf(v.x); o[1] = f2bf(v.y); o[2] = f2bf(v.z); o[3] = f2bf(v.w);
    reinterpret_cast<u16x4*>(out)[idx] = o;
  }
}

// ---------- pre-pass: mask * (-log2e)  (for stage-1 sigmoid via exp2) ----------
__global__ void k_mask(const float* __restrict__ in, float* __restrict__ out, int n4) {
  int i = blockIdx.x * blockDim.x + threadIdx.x;
  int stride = gridDim.x * blockDim.x;
  for (int idx = i; idx < n4; idx += stride) {
    float4 v = reinterpret_cast<const float4*>(in)[idx];
    v.x *= -LOG2E_; v.y *= -LOG2E_; v.z *= -LOG2E_; v.w *= -LOG2E_;
    reinterpret_cast<float4*>(out)[idx] = v;
  }
}

// ---------- pre-pass: W[512][nc] f32 -> Wt[nc][512] bf16, cols<512 scaled by qs ----------
__global__ void k_wt(const float* __restrict__ W, u16* __restrict__ Wt, int ncols, float qs) {
  int idx = blockIdx.x * 256 + threadIdx.x;
  if (idx >= ncols * 512) return;
  int c = idx >> 9, k = idx & 511;
  float v = W[k * ncols + c];
  if (c < 512) v *= qs;
  Wt[idx] = f2bf(v);
}

// ---------- GEMM (m97 structure): 128x128 tile, BK=32, LDS double-buffered ----------
// MODE 0: scatter epilogue -> q,k [BH][N][D] bf16, v -> vt [BH][D][N] bf16 (packed u16x4).
// MODE 1: f32 out. SQ: scale bias of q-part (cols<512) by QSL2E_ to match the W-fold.
template<int NC, int MODE, bool SQ>
__global__ __launch_bounds__(256) void k_gemm(
    const u16* __restrict__ A, const u16* __restrict__ Wt, const float* __restrict__ bias,
    u16* __restrict__ qo, u16* __restrict__ ko, u16* __restrict__ vto, float* __restrict__ fo)
{
  __shared__ __attribute__((aligned(16))) u16 As[2][128 * 32];
  __shared__ __attribute__((aligned(16))) u16 Bs[2][128 * 32];
  const int wv = threadIdx.x >> 6, ln = threadIdx.x & 63;
  const int lr = ln & 15, lg = ln >> 4;
  const int wr = wv >> 1, wc = wv & 1;
  const int r0 = blockIdx.x * 128;
  const int c0 = blockIdx.y * 128;

  auto stage = [&](int bufi, int kk) {
#pragma unroll
    for (int q = 0; q < 2; ++q) {
      int L = (wv * 2 + q) * 1024 + ln * 16;   // linear swizzled LDS byte offset
      int row = L >> 6;
      int col = ((L & 63) ^ (((row >> 1) & 3) << 4)) >> 1;  // inverse-swizzled source col
      gload_lds16(A  + (size_t)(r0 + row) * 512 + kk + col, (char*)As[bufi] + (wv * 2 + q) * 1024);
      gload_lds16(Wt + (size_t)(c0 + row) * 512 + kk + col, (char*)Bs[bufi] + (wv * 2 + q) * 1024);
    }
  };
  auto swzld = [&](const u16* tile, int row, int colb) -> bf16x8 {
    int byte = (row << 6) + (colb ^ (((row >> 1) & 3) << 4));
    return __builtin_bit_cast(bf16x8, *reinterpret_cast<const u16x8*>((const char*)tile + byte));
  };

  f32x4 acc[4][4] = {};
  stage(0, 0);
  int buf = 0;
  for (int kk = 0; kk < 512; kk += 32) {
    __syncthreads();
    if (kk + 32 < 512) stage(buf ^ 1, kk + 32);
    bf16x8 af[4], bfb[4];
#pragma unroll
    for (int m = 0; m < 4; ++m) af[m]  = swzld(As[buf], wr * 64 + m * 16 + lr, lg * 16);
#pragma unroll
    for (int n = 0; n < 4; ++n) bfb[n] = swzld(Bs[buf], wc * 64 + n * 16 + lr, lg * 16);
#pragma unroll
    for (int m = 0; m < 4; ++m)
#pragma unroll
      for (int n = 0; n < 4; ++n)
        acc[m][n] = mfma16(af[m], bfb[n], acc[m][n]);
    buf ^= 1;
  }

#pragma unroll
  for (int m = 0; m < 4; ++m)
#pragma unroll
    for (int n = 0; n < 4; ++n) {
      const int gc  = c0 + wc * 64 + n * 16 + lr;
      const int gr0 = r0 + wr * 64 + m * 16 + lg * 4;     // 4 consecutive rows
      const float bsc = (SQ && gc < 512) ? QSL2E_ : 1.f;
      const float bv = bias[gc] * bsc;
      if (MODE == 0) {
        const int part = gc >> 9, cc = gc & 511;
        const int hh = cc >> 6, dd = cc & 63;
        const int bb = gr0 >> 10, nn = gr0 & 1023;
        const int bh = bb * H_ + hh;
        if (part == 2) {
          u16x4 w;
#pragma unroll
          for (int r = 0; r < 4; ++r) w[r] = f2bf(acc[m][n][r] + bv);
          *reinterpret_cast<u16x4*>(&vto[((size_t)(bh * D_ + dd)) * N_ + nn]) = w;
        } else {
          u16* dst = (part == 0 ? qo : ko) + ((size_t)(bh * N_ + nn)) * D_ + dd;
#pragma unroll
          for (int r = 0; r < 4; ++r) dst[(size_t)r * D_] = f2bf(acc[m][n][r] + bv);
        }
      } else {
#pragma unroll
        for (int r = 0; r < 4; ++r)
          fo[(size_t)(gr0 + r) * NC + gc] = acc[m][n][r] + bv;
      }
    }
}

// ---------- attention (swapped-QK^T) ----------
// QK^T computed as mfma(K_frag, Q_frag) -> lane holds S^T[j][i]: i = lr (one query
// per lane), j = js*16 + lg*4 + r (16 keys per lane). Row-work is lane-local; P goes
// to per-wave LDS row-major [i][j] (ds_write_b64), read back as A-fragment.
// STAGE 1: P = sigmoid(S * mask)           mask pre-scaled by -log2e, prefetched
// STAGE 2: P = exp2(S') unnormalized       SCALE*log2e folded into W2 q-cols; /sum at end
template<int STAGE>
__global__ __launch_bounds__(512, 4) void k_attn(
    const u16* __restrict__ Q, const u16* __restrict__ K, const u16* __restrict__ Vt,
    const float* __restrict__ mask, u16* __restrict__ O)
{
  __shared__ __attribute__((aligned(16))) u16 Kb[2][64 * 64];
  __shared__ __attribute__((aligned(16))) u16 Vb[2][64 * 64];
  __shared__ __attribute__((aligned(16))) u16 pbuf[8][16][72];
  const int wv = threadIdx.x >> 6, ln = threadIdx.x & 63;
  const int lr = ln & 15, lg = ln >> 4;
  const int bh = blockIdx.y;
  const int i0 = blockIdx.x * 128 + wv * 16;
  const size_t base = (size_t)bh * N_ * D_;

  auto stageKV = [&](int bufi, int jt2) {
    int L = wv * 1024 + ln * 16;
    int row = L >> 7;
    int col = ((L & 127) ^ ((row & 7) << 4)) >> 1;
    gload_lds16(K  + base + (size_t)(jt2 + row) * 64 + col,  (char*)Kb[bufi] + wv * 1024);
    gload_lds16(Vt + base + (size_t)row * 1024 + jt2 + col,  (char*)Vb[bufi] + wv * 1024);
  };
  auto swzld = [&](const u16* tile, int row, int colb) -> bf16x8 {
    int byte = (row << 7) + (colb ^ ((row & 7) << 4));
    return __builtin_bit_cast(bf16x8, *reinterpret_cast<const u16x8*>((const char*)tile + byte));
  };

  // Q as the B-operand: lane holds query row i=lr, k-elems d = lg*8..+7
  bf16x8 aq0 = ld8(Q + base + (size_t)(i0 + lr) * D_ + lg * 8);
  bf16x8 aq1 = ld8(Q + base + (size_t)(i0 + lr) * D_ + 32 + lg * 8);

  f32x4 acco[4] = {};
  float ssum_ln = 0.f;    // per-lane partial softmax denom (for query i=lr)

  // stage-1 mask prefetch registers
  float4 mk[4];
  const float* mrow = mask + (size_t)(i0 + lr) * N_;
  auto loadmask = [&](int jt2) {
#pragma unroll
    for (int js = 0; js < 4; ++js)
      mk[js] = *reinterpret_cast<const float4*>(&mrow[jt2 + js * 16 + lg * 4]);
  };
  if (STAGE == 1) loadmask(0);

  stageKV(0, 0);
  int buf = 0;
  for (int jt = 0; jt < N_; jt += 64) {
    __syncthreads();
    if (jt + 64 < N_) stageKV(buf ^ 1, jt + 64);

    // S^T tiles: A = K rows j, B = Q rows i
    f32x4 s[4];
    __builtin_amdgcn_s_setprio(1);
#pragma unroll
    for (int js = 0; js < 4; ++js) {
      int krow = js * 16 + lr;
      bf16x8 bk0 = swzld(Kb[buf], krow, lg * 16);
      bf16x8 bk1 = swzld(Kb[buf], krow, 64 + lg * 16);
      f32x4 z = {};
      z = mfma16(bk0, aq0, z);
      z = mfma16(bk1, aq1, z);
      s[js] = z;
    }
    __builtin_amdgcn_s_setprio(0);

    if (STAGE == 1) {
#pragma unroll
      for (int js = 0; js < 4; ++js) {
        u16x4 w;
#pragma unroll
        for (int r = 0; r < 4; ++r) {
          float mkr = (r == 0) ? mk[js].x : (r == 1) ? mk[js].y : (r == 2) ? mk[js].z : mk[js].w;
          float e = exp2f(s[js][r] * mkr);               // exp(-x*mask')
          w[r] = f2bf(__builtin_amdgcn_rcpf(1.f + e));   // sigmoid
        }
        *reinterpret_cast<u16x4*>(&pbuf[wv][lr][js * 16 + lg * 4]) = w;
      }
      if (jt + 64 < N_) loadmask(jt + 64);   // prefetch next tile's mask (hides under PV+QK)
    } else {
      float ps = 0.f;
#pragma unroll
      for (int js = 0; js < 4; ++js) {
        u16x4 w;
#pragma unroll
        for (int r = 0; r < 4; ++r) {
          float p = exp2f(s[js][r]);                     // unnormalized, logits bounded
          ps += p;
          w[r] = f2bf(p);
        }
        *reinterpret_cast<u16x4*>(&pbuf[wv][lr][js * 16 + lg * 4]) = w;
      }
      ssum_ln += ps;
    }

    // PV: P[16x64] @ V[64x64]
    bf16x8 ap0 = ld8(&pbuf[wv][lr][lg * 8]);
    bf16x8 ap1 = ld8(&pbuf[wv][lr][32 + lg * 8]);
    __builtin_amdgcn_s_setprio(1);
#pragma unroll
    for (int db = 0; db < 4; ++db) {
      bf16x8 bv0 = swzld(Vb[buf], db * 16 + lr, lg * 16);
      bf16x8 bv1 = swzld(Vb[buf], db * 16 + lr, 64 + lg * 16);
      acco[db] = mfma16(ap1, bv1, mfma16(ap0, bv0, acco[db]));
    }
    __builtin_amdgcn_s_setprio(0);
    buf ^= 1;
  }

  float inv[4];
  if (STAGE == 2) {
    float st = ssum_ln;
    st += __shfl_xor(st, 16);
    st += __shfl_xor(st, 32);    // total denom for query i=lr (uniform over lg)
#pragma unroll
    for (int r = 0; r < 4; ++r)
      inv[r] = __builtin_amdgcn_rcpf(__shfl(st, lg * 4 + r));  // denom for output row
  }

  // epilogue: transpose O tile through pbuf -> 2x16B coalesced stores per lane
#pragma unroll
  for (int db = 0; db < 4; ++db)
#pragma unroll
    for (int r = 0; r < 4; ++r) {
      float v = acco[db][r];
      if (STAGE == 2) v *= inv[r];
      pbuf[wv][lg * 4 + r][db * 16 + lr] = f2bf(v);     // row i, col d
    }
  bf16x8 o0v = ld8(&pbuf[wv][lr][lg * 8]);              // same-wave LDS, compiler waits
  bf16x8 o1v = ld8(&pbuf[wv][lr][32 + lg * 8]);
  const int bb = bh >> 3, hh = bh & 7;
  u16* orow = O + (size_t)(bb * N_ + i0 + lr) * DIM_ + hh * D_;
  *reinterpret_cast<u16x8*>(orow + lg * 8)      = __builtin_bit_cast(u16x8, o0v);
  *reinterpret_cast<u16x8*>(orow + 32 + lg * 8) = __builtin_bit_cast(u16x8, o1v);
}

extern "C" void kernel_launch(void* const* d_in, const int* in_sizes, int n_in,
                              void* d_out, int out_size, void* d_ws, size_t ws_size,
                              hipStream_t stream)
{
  const float* x    = (const float*)d_in[0];
  const float* mask = (const float*)d_in[1];
  const float* W1   = (const float*)d_in[2];
  const float* b1   = (const float*)d_in[3];
  const float* W2   = (const float*)d_in[4];
  const float* b2   = (const float*)d_in[5];
  const float* W3   = (const float*)d_in[6];
  const float* b3   = (const float*)d_in[7];
  float* out = (float*)d_out;

  char* ws = (char*)d_ws;
  size_t off = 0;
  auto alloc = [&](size_t bytes) { char* p = ws + off; off += (bytes + 255) & ~255ULL; return p; };
  u16*   W1t = (u16*)alloc((size_t)1536 * 512 * 2);
  u16*   W2t = (u16*)alloc((size_t)1536 * 512 * 2);
  u16*   W3t = (u16*)alloc((size_t)512 * 512 * 2);
  u16*   xb  = (u16*)alloc((size_t)M_ * DIM_ * 2);      // x bf16; reused as out2
  u16*   q   = (u16*)alloc((size_t)BH_ * N_ * D_ * 2);
  u16*   k   = (u16*)alloc((size_t)BH_ * N_ * D_ * 2);
  u16*   vt  = (u16*)alloc((size_t)BH_ * N_ * D_ * 2);
  u16*   o1  = (u16*)alloc((size_t)M_ * DIM_ * 2);
  float* mk  = (float*)alloc((size_t)N_ * N_ * 4);      // mask * (-log2e)
  u16*   o2  = xb;

  k_cvt<<<2048, 256, 0, stream>>>(x, xb, M_ * DIM_ / 4);
  k_mask<<<1024, 256, 0, stream>>>(mask, mk, N_ * N_ / 4);
  k_wt<<<(1536 * 512 + 255) / 256, 256, 0, stream>>>(W1, W1t, 1536, 1.f);
  k_wt<<<(1536 * 512 + 255) / 256, 256, 0, stream>>>(W2, W2t, 1536, QSL2E_);
  k_wt<<<(512 * 512 + 255) / 256, 256, 0, stream>>>(W3, W3t, 512, 1.f);

  dim3 g1(M_ / 128, 1536 / 128);
  k_gemm<1536, 0, false><<<g1, 256, 0, stream>>>(xb, W1t, b1, q, k, vt, nullptr);

  dim3 ga(N_ / 128, BH_);
  k_attn<1><<<ga, 512, 0, stream>>>(q, k, vt, mk, o1);

  k_gemm<1536, 0, true><<<g1, 256, 0, stream>>>(o1, W2t, b2, q, k, vt, nullptr);

  k_attn<2><<<ga, 512, 0, stream>>>(q, k, vt, mk, o2);

  dim3 g3(M_ / 128, 512 / 128);
  k_gemm<512, 1, false><<<g3, 256, 0, stream>>>(o2, W3t, b3, nullptr, nullptr, nullptr, out);
}